// Round 1
// baseline (94.831 us; speedup 1.0000x reference)
//
#include <hip/hip_runtime.h>

// RoiPoolingConv: crop_and_resize (bilinear, 14x14) + 2x2 max pool -> (512,7,7,512)
// fm: (38,50,512) f32 contiguous; rois: (512,5) f32 [batch, x1, y1, x2, y2]
// out[n,ph,pw,c] = max over (jy,ix in {0,1}) of bilinear(fm, y(2ph+jy), x(2pw+ix))[c]

#define FM_H 38
#define FM_W 50
#define NCH  512
#define NPP  49   // 7*7

__global__ __launch_bounds__(128) void roi_pool_kernel(
    const float* __restrict__ fm,
    const float* __restrict__ rois,
    float* __restrict__ out)
{
    const int bi = blockIdx.x;          // n*49 + ph*7 + pw
    const int n  = bi / NPP;
    const int r  = bi - n * NPP;
    const int ph = r / 7;
    const int pw = r - ph * 7;
    const int c  = threadIdx.x * 4;     // 4 channels per thread (float4)

    // ROI box, normalized exactly like the reference (divide, not mul-by-recip)
    const float x1 = rois[n * 5 + 1];
    const float y1 = rois[n * 5 + 2];
    const float x2 = rois[n * 5 + 3];
    const float y2 = rois[n * 5 + 4];
    const float ny1 = y1 / 600.0f, ny2 = y2 / 600.0f;
    const float nx1 = x1 / 800.0f, nx2 = x2 / 800.0f;

    // Sample-row coords for j = 2*ph + {0,1}
    int yA[2], yB[2]; float wy[2];
#pragma unroll
    for (int jy = 0; jy < 2; ++jy) {
        const int j = 2 * ph + jy;
        const float t  = (float)j / 13.0f;                  // ty = arange/13 (f32)
        const float yy = (ny1 + t * (ny2 - ny1)) * 37.0f;   // * (H-1)
        const float yf = floorf(yy);
        int yi = (int)yf;
        yi = min(max(yi, 0), FM_H - 1);
        yA[jy] = yi;
        yB[jy] = min(yi + 1, FM_H - 1);
        wy[jy] = yy - yf;                                   // from UNclipped floor
    }
    // Sample-col coords for i = 2*pw + {0,1}
    int xA[2], xB[2]; float wx[2];
#pragma unroll
    for (int ix = 0; ix < 2; ++ix) {
        const int i = 2 * pw + ix;
        const float t  = (float)i / 13.0f;
        const float xx = (nx1 + t * (nx2 - nx1)) * 49.0f;   // * (W-1)
        const float xf = floorf(xx);
        int xi = (int)xf;
        xi = min(max(xi, 0), FM_W - 1);
        xA[ix] = xi;
        xB[ix] = min(xi + 1, FM_W - 1);
        wx[ix] = xx - xf;
    }

    float4 best = make_float4(-INFINITY, -INFINITY, -INFINITY, -INFINITY);
#pragma unroll
    for (int jy = 0; jy < 2; ++jy) {
#pragma unroll
        for (int ix = 0; ix < 2; ++ix) {
            const float4 f00 = *(const float4*)(fm + ((size_t)(yA[jy] * FM_W + xA[ix]) * NCH) + c);
            const float4 f01 = *(const float4*)(fm + ((size_t)(yA[jy] * FM_W + xB[ix]) * NCH) + c);
            const float4 f10 = *(const float4*)(fm + ((size_t)(yB[jy] * FM_W + xA[ix]) * NCH) + c);
            const float4 f11 = *(const float4*)(fm + ((size_t)(yB[jy] * FM_W + xB[ix]) * NCH) + c);
            const float a = wx[ix], b = wy[jy];
            const float ia = 1.0f - a, ib = 1.0f - b;
            // reference order: top = f00*(1-wx) + f01*wx; v = top*(1-wy) + bot*wy
            float4 v;
            {
                const float tx_ = f00.x * ia + f01.x * a;
                const float bx_ = f10.x * ia + f11.x * a;
                v.x = tx_ * ib + bx_ * b;
                const float ty_ = f00.y * ia + f01.y * a;
                const float by_ = f10.y * ia + f11.y * a;
                v.y = ty_ * ib + by_ * b;
                const float tz_ = f00.z * ia + f01.z * a;
                const float bz_ = f10.z * ia + f11.z * a;
                v.z = tz_ * ib + bz_ * b;
                const float tw_ = f00.w * ia + f01.w * a;
                const float bw_ = f10.w * ia + f11.w * a;
                v.w = tw_ * ib + bw_ * b;
            }
            best.x = fmaxf(best.x, v.x);
            best.y = fmaxf(best.y, v.y);
            best.z = fmaxf(best.z, v.z);
            best.w = fmaxf(best.w, v.w);
        }
    }

    *(float4*)(out + (size_t)bi * NCH + c) = best;
}

extern "C" void kernel_launch(void* const* d_in, const int* in_sizes, int n_in,
                              void* d_out, int out_size, void* d_ws, size_t ws_size,
                              hipStream_t stream) {
    const float* fm   = (const float*)d_in[0];   // (1,38,50,512) f32
    const float* rois = (const float*)d_in[1];   // (512,5) f32
    float* out = (float*)d_out;                  // (1,512,7,7,512) f32

    const int N = in_sizes[1] / 5;               // 512 rois
    const int blocks = N * NPP;                  // one block per (roi, ph, pw)
    roi_pool_kernel<<<blocks, NCH / 4, 0, stream>>>(fm, rois, out);
}

// Round 2
// 89.039 us; speedup vs baseline: 1.0651x; 1.0651x over previous
//
#include <hip/hip_runtime.h>

// RoiPoolingConv: crop_and_resize (bilinear, 14x14 grid) + 2x2 max pool
// fm: (38,50,512) f32; rois: (512,5) f32 [batch, x1, y1, x2, y2]
// out[n,ph,pw,c] = max over (jy,ix in {0,1}) of bilinear sample (2ph+jy, 2pw+ix)
//
// Optimization (R2): the two samples per axis in a pool window are ~1.25 cells
// apart on average, so their corner rows/cols frequently coincide or abut.
// Block-uniform 3-way case split per axis dedups corner loads: 16 -> ~9.6 avg.

#define FM_H 38
#define FM_W 50
#define NCH  512
#define NPP  49   // 7*7

__device__ __forceinline__ float4 lerp4(const float4 a, const float4 b, const float w) {
    const float iw = 1.0f - w;
    return make_float4(a.x * iw + b.x * w,
                       a.y * iw + b.y * w,
                       a.z * iw + b.z * w,
                       a.w * iw + b.w * w);
}

__device__ __forceinline__ float4 max4(const float4 a, const float4 b) {
    return make_float4(fmaxf(a.x, b.x), fmaxf(a.y, b.y),
                       fmaxf(a.z, b.z), fmaxf(a.w, b.w));
}

#define LD4(p) (*(const float4*)(p))

__global__ __launch_bounds__(128) void roi_pool_kernel(
    const float* __restrict__ fm,
    const float* __restrict__ rois,
    float* __restrict__ out)
{
    const int bi = blockIdx.x;          // n*49 + ph*7 + pw
    const int n  = bi / NPP;
    const int r  = bi - n * NPP;
    const int ph = r / 7;
    const int pw = r - ph * 7;
    const int c  = threadIdx.x * 4;     // 4 channels per thread (float4)

    // ROI box (block-uniform). Combined scale: (v/IM)* (dim-1).
    const float x1 = rois[n * 5 + 1];
    const float y1 = rois[n * 5 + 2];
    const float x2 = rois[n * 5 + 3];
    const float y2 = rois[n * 5 + 4];
    const float SX = 49.0f / 800.0f;    // (W-1)/IM_W
    const float SY = 37.0f / 600.0f;    // (H-1)/IM_H

    // --- x samples: i = 2*pw + {0,1} ---
    int   xA0, xB0, xA1, xB1;
    float wx0, wx1;
    {
        const float t0 = (float)(2 * pw)     * (1.0f / 13.0f);
        const float t1 = (float)(2 * pw + 1) * (1.0f / 13.0f);
        const float dx = x2 - x1;
        const float xx0 = (x1 + t0 * dx) * SX;
        const float xx1 = (x1 + t1 * dx) * SX;
        const float xf0 = floorf(xx0), xf1 = floorf(xx1);
        int a0 = (int)xf0; a0 = min(max(a0, 0), FM_W - 1);
        int a1 = (int)xf1; a1 = min(max(a1, 0), FM_W - 1);
        xA0 = a0; xB0 = min(a0 + 1, FM_W - 1);
        xA1 = a1; xB1 = min(a1 + 1, FM_W - 1);
        wx0 = xx0 - xf0;                 // weights from UNclipped floor
        wx1 = xx1 - xf1;
    }
    // --- y samples: j = 2*ph + {0,1} ---
    int   yA0, yB0, yA1, yB1;
    float wy0, wy1;
    {
        const float t0 = (float)(2 * ph)     * (1.0f / 13.0f);
        const float t1 = (float)(2 * ph + 1) * (1.0f / 13.0f);
        const float dy = y2 - y1;
        const float yy0 = (y1 + t0 * dy) * SY;
        const float yy1 = (y1 + t1 * dy) * SY;
        const float yf0 = floorf(yy0), yf1 = floorf(yy1);
        int a0 = (int)yf0; a0 = min(max(a0, 0), FM_H - 1);
        int a1 = (int)yf1; a1 = min(max(a1, 0), FM_H - 1);
        yA0 = a0; yB0 = min(a0 + 1, FM_H - 1);
        yA1 = a1; yB1 = min(a1 + 1, FM_H - 1);
        wy0 = yy0 - yf0;
        wy1 = yy1 - yf1;
    }

    // Case per axis (block-uniform): 0 = same cell, 1 = adjacent (share one
    // corner), 2 = disjoint. Note xA1==xA0 implies xB1==xB0.
    const int xcs = (xA1 == xA0) ? 0 : ((xA1 == xB0) ? 1 : 2);
    const int ycs = (yA1 == yA0) ? 0 : ((yA1 == yB0) ? 1 : 2);

    const float* fmc = fm + c;

    // x-interpolate one fm row at both sample columns, with col dedup.
    auto interpX = [&](int row, float4& t0, float4& t1) {
        const float* bp = fmc + (size_t)row * (FM_W * NCH);
        if (xcs == 0) {
            const float4 v0 = LD4(bp + xA0 * NCH);
            const float4 v1 = LD4(bp + xB0 * NCH);
            t0 = lerp4(v0, v1, wx0);
            t1 = lerp4(v0, v1, wx1);
        } else if (xcs == 1) {
            const float4 v0 = LD4(bp + xA0 * NCH);
            const float4 v1 = LD4(bp + xB0 * NCH);   // == xA1
            const float4 v2 = LD4(bp + xB1 * NCH);
            t0 = lerp4(v0, v1, wx0);
            t1 = lerp4(v1, v2, wx1);
        } else {
            const float4 v0 = LD4(bp + xA0 * NCH);
            const float4 v1 = LD4(bp + xB0 * NCH);
            const float4 v2 = LD4(bp + xA1 * NCH);
            const float4 v3 = LD4(bp + xB1 * NCH);
            t0 = lerp4(v0, v1, wx0);
            t1 = lerp4(v2, v3, wx1);
        }
    };

    float4 best;
    if (ycs == 0) {
        // rows {yA0, yB0}; both y-samples use the same row pair
        float4 a0, a1, b0, b1;
        interpX(yA0, a0, a1);
        interpX(yB0, b0, b1);
        const float4 s00 = lerp4(a0, b0, wy0);
        const float4 s01 = lerp4(a1, b1, wy0);
        const float4 s10 = lerp4(a0, b0, wy1);
        const float4 s11 = lerp4(a1, b1, wy1);
        best = max4(max4(s00, s01), max4(s10, s11));
    } else if (ycs == 1) {
        // rows {yA0, yB0==yA1, yB1}
        float4 a0, a1, b0, b1, e0, e1;
        interpX(yA0, a0, a1);
        interpX(yB0, b0, b1);
        interpX(yB1, e0, e1);
        const float4 s00 = lerp4(a0, b0, wy0);
        const float4 s01 = lerp4(a1, b1, wy0);
        const float4 s10 = lerp4(b0, e0, wy1);
        const float4 s11 = lerp4(b1, e1, wy1);
        best = max4(max4(s00, s01), max4(s10, s11));
    } else {
        // 4 distinct rows
        float4 a0, a1, b0, b1, d0, d1, e0, e1;
        interpX(yA0, a0, a1);
        interpX(yB0, b0, b1);
        interpX(yA1, d0, d1);
        interpX(yB1, e0, e1);
        const float4 s00 = lerp4(a0, b0, wy0);
        const float4 s01 = lerp4(a1, b1, wy0);
        const float4 s10 = lerp4(d0, e0, wy1);
        const float4 s11 = lerp4(d1, e1, wy1);
        best = max4(max4(s00, s01), max4(s10, s11));
    }

    *(float4*)(out + (size_t)bi * NCH + c) = best;
}

extern "C" void kernel_launch(void* const* d_in, const int* in_sizes, int n_in,
                              void* d_out, int out_size, void* d_ws, size_t ws_size,
                              hipStream_t stream) {
    const float* fm   = (const float*)d_in[0];   // (1,38,50,512) f32
    const float* rois = (const float*)d_in[1];   // (512,5) f32
    float* out = (float*)d_out;                  // (1,512,7,7,512) f32

    const int N = in_sizes[1] / 5;               // 512 rois
    const int blocks = N * NPP;                  // one block per (roi, ph, pw)
    roi_pool_kernel<<<blocks, NCH / 4, 0, stream>>>(fm, rois, out);
}